// Round 8
// baseline (341.293 us; speedup 1.0000x reference)
//
#include <hip/hip_runtime.h>
#include <hip/hip_bf16.h>
#include <cstdint>

#define B_   8
#define L_   1024
#define F_   1024
#define H_   256
#define NH_  8
#define LBL_ 4766
#define M_   (B_*L_)    // 8192
#define OD_  (NH_*H_)   // 2048
#define NCM  (LBL_*LBL_)     // 22714756
#define MP_EPB 16384
#define MP_NB  ((NCM + MP_EPB - 1) / MP_EPB)   // 1387
#define NCH  32          // k-chunks per GEMV (K=2048 / KC=64)

typedef unsigned short u16;
typedef unsigned int   u32;
typedef __attribute__((ext_vector_type(8))) short short8;
typedef __attribute__((ext_vector_type(4))) float float4v;

#define BF16_ONES_PAIR 0x3f803f80u

__device__ __forceinline__ float bf2f(u32 u) { return __uint_as_float(u << 16); }
__device__ __forceinline__ u16 f2bf(float f) {
    u32 u = __float_as_uint(f);
    u32 r = 0x7fffu + ((u >> 16) & 1u);
    return (u16)((u + r) >> 16);
}

struct f8 { float v[8]; };

__device__ __forceinline__ float ldS(const void* p, size_t i, bool bf) {
    return bf ? bf2f(((const u16*)p)[i]) : ((const float*)p)[i];
}
__device__ __forceinline__ float4 ld4(const void* p, size_t i, bool bf) {
    if (bf) {
        uint2 u = *(const uint2*)((const u16*)p + i);
        return make_float4(bf2f(u.x & 0xffff), bf2f(u.x >> 16),
                           bf2f(u.y & 0xffff), bf2f(u.y >> 16));
    }
    return *(const float4*)((const float*)p + i);
}
__device__ __forceinline__ f8 ld8(const void* p, size_t i, bool bf) {
    f8 r;
    if (bf) {
        uint4 u = *(const uint4*)((const u16*)p + i);
        r.v[0]=bf2f(u.x&0xffff); r.v[1]=bf2f(u.x>>16);
        r.v[2]=bf2f(u.y&0xffff); r.v[3]=bf2f(u.y>>16);
        r.v[4]=bf2f(u.z&0xffff); r.v[5]=bf2f(u.z>>16);
        r.v[6]=bf2f(u.w&0xffff); r.v[7]=bf2f(u.w>>16);
    } else {
        const float* q = (const float*)p + i;
        float4 a = *(const float4*)q, b = *(const float4*)(q+4);
        r.v[0]=a.x; r.v[1]=a.y; r.v[2]=a.z; r.v[3]=a.w;
        r.v[4]=b.x; r.v[5]=b.y; r.v[6]=b.z; r.v[7]=b.w;
    }
    return r;
}

__device__ __forceinline__ float wave_sum(float v) {
    #pragma unroll
    for (int m = 1; m < 64; m <<= 1) v += __shfl_xor(v, m, 64);
    return v;
}
__device__ __forceinline__ float wave_max(float v) {
    #pragma unroll
    for (int m = 1; m < 64; m <<= 1) v = fmaxf(v, __shfl_xor(v, m, 64));
    return v;
}
__device__ __forceinline__ float blk_sum(float v, float* sh) {
    v = wave_sum(v);
    int w = threadIdx.x >> 6, nw = blockDim.x >> 6;
    if ((threadIdx.x & 63) == 0) sh[w] = v;
    __syncthreads();
    float s = sh[0];
    for (int i = 1; i < nw; ++i) s += sh[i];
    __syncthreads();
    return s;
}
__device__ __forceinline__ float blk_max(float v, float* sh) {
    v = wave_max(v);
    int w = threadIdx.x >> 6, nw = blockDim.x >> 6;
    if ((threadIdx.x & 63) == 0) sh[w] = v;
    __syncthreads();
    float s = sh[0];
    for (int i = 1; i < nw; ++i) s = fmaxf(s, sh[i]);
    __syncthreads();
    return s;
}

// ---- fused prep: LN0 (wave-per-row, 4 rows/block) | 3 weight transposes ----
__global__ __launch_bounds__(256) void prep_k(const void* __restrict__ hv,
        const void* __restrict__ g0, const void* __restrict__ b0, u16* __restrict__ x0,
        const void* __restrict__ w_in, u16* __restrict__ wt1,
        const void* __restrict__ w_h,  u16* __restrict__ wt2,
        const void* __restrict__ aw1,  u16* __restrict__ wt3,
        const u32* __restrict__ probe) {
    __shared__ u16 tile[64][65];
    bool bf = (probe[0] == BF16_ONES_PAIR);
    int blk = blockIdx.x, t = threadIdx.x;
    if (blk < M_/4) {                      // LN0: one wave per row, no barriers
        int row = (blk << 2) + (t >> 6);
        int l = t & 63;
        size_t base = (size_t)row * F_;
        float4 vv[4];
        float s = 0.f, q = 0.f;
        #pragma unroll
        for (int j = 0; j < 4; ++j) {
            float4 v = ld4(hv, base + l * 4 + j * 256, bf);
            vv[j] = v;
            s += v.x + v.y + v.z + v.w;
            q += v.x*v.x + v.y*v.y + v.z*v.z + v.w*v.w;
        }
        s = wave_sum(s);
        q = wave_sum(q);
        float mean = s * (1.f / F_);
        float rstd = rsqrtf(q * (1.f / F_) - mean * mean + 1e-6f);
        #pragma unroll
        for (int j = 0; j < 4; ++j) {
            int off = l * 4 + j * 256;
            float4 gg = ld4(g0, off, bf);
            float4 bb = ld4(b0, off, bf);
            float4 v = vv[j];
            u32 o0 = f2bf((v.x - mean) * rstd * gg.x + bb.x)
                   | ((u32)f2bf((v.y - mean) * rstd * gg.y + bb.y) << 16);
            u32 o1 = f2bf((v.z - mean) * rstd * gg.z + bb.z)
                   | ((u32)f2bf((v.w - mean) * rstd * gg.w + bb.w) << 16);
            *(uint2*)(x0 + base + off) = make_uint2(o0, o1);
        }
        return;
    }
    blk -= M_/4;
    const void* W = nullptr; u16* WT = nullptr; int K = 0, N = 0, kt = 0, nt = 0;
    if (blk < 64)      { W = w_in; WT = wt1; K = F_; N = H_; kt = blk & 15; nt = blk >> 4; }
    else if (blk < 80) { int j = blk - 64; W = w_h; WT = wt2; K = H_; N = H_; kt = j & 3; nt = j >> 2; }
    else               { int j = blk - 80; W = aw1; WT = wt3; K = H_; N = 64; kt = j; nt = 0; }
    int kt0 = kt * 64, nt0 = nt * 64;
    int r = t >> 2, cq = (t & 3) * 16;
    #pragma unroll
    for (int j = 0; j < 4; ++j) {
        float4 v = ld4(W, (size_t)(kt0 + r) * N + nt0 + cq + j * 4, bf);
        tile[r][cq + j*4 + 0] = f2bf(v.x);
        tile[r][cq + j*4 + 1] = f2bf(v.y);
        tile[r][cq + j*4 + 2] = f2bf(v.z);
        tile[r][cq + j*4 + 3] = f2bf(v.w);
    }
    __syncthreads();
    #pragma unroll
    for (int j = 0; j < 4; ++j) {
        int k = cq + j * 4;
        u32 a0 = tile[k+0][r], a1 = tile[k+1][r], a2 = tile[k+2][r], a3 = tile[k+3][r];
        uint2 o; o.x = a0 | (a1 << 16); o.y = a2 | (a3 << 16);
        *(uint2*)(WT + (size_t)(nt0 + r) * K + kt0 + k) = o;
    }
}

// ---- MFMA bf16 GEMM, 64x128 tile, dbuf, 1 barrier/K-step.
//      stats: plain partial stores into st[2][M] (y-block owns half the cols);
//      statin layout [2][M] summed on read. ----
__global__ __launch_bounds__(256) void gemm_mfma(const u16* __restrict__ Ap, int amode,
        const float2* __restrict__ statin, const void* __restrict__ g,
        const void* __restrict__ bta, const u16* __restrict__ WT,
        const void* __restrict__ bias, u16* __restrict__ C,
        float* __restrict__ statout, int M, int N, int K,
        const u32* __restrict__ probe) {
    __shared__ short8 As[2][64][5];
    __shared__ short8 Bs[2][128][5];
    bool pbf = (probe[0] == BF16_ONES_PAIR);
    int t = threadIdx.x;
    int m0 = blockIdx.x * 64, n0 = blockIdx.y * 128;
    int r = t >> 2, kq = t & 3;            // A staging
    int rb = t & 127, hb = t >> 7;         // B staging: row rb, k-half hb
    int l = t & 63, w = t >> 6;
    int q = l >> 4, ml = l & 15;
    float4v acc[8];
    #pragma unroll
    for (int nt = 0; nt < 8; ++nt)
        #pragma unroll
        for (int i = 0; i < 4; ++i) acc[nt][i] = 0.f;
    float stm = 0.f, str = 1.f;
    if (amode == 1) {
        float2 s0 = statin[m0 + r];
        float2 s1 = statin[M + m0 + r];
        float ssum = s0.x + s1.x, ssq = s0.y + s1.y;
        float mm = ssum * (1.f / K);
        stm = mm;
        str = rsqrtf(ssq * (1.f / K) - mm * mm + 1e-6f);
    }
    const size_t arow = (size_t)(m0 + r) * K;
    const size_t brow = (size_t)(n0 + rb) * K + hb * 16;
    auto loadA = [&](int kk) -> short8 {
        if (amode == 1) {
            f8 a  = ld8(Ap, arow + kk, true);
            f8 gg = ld8(g, kk, pbf);
            f8 bb = ld8(bta, kk, pbf);
            short8 pa;
            #pragma unroll
            for (int j = 0; j < 8; ++j)
                pa[j] = (short)f2bf((a.v[j] - stm) * str * gg.v[j] + bb.v[j]);
            return pa;
        }
        return *(const short8*)(Ap + arow + kk);
    };
    // prologue: stage K-step 0 into buffer 0
    {
        short8 pa = loadA(kq * 8);
        short8 pb0 = *(const short8*)(WT + brow);
        short8 pb1 = *(const short8*)(WT + brow + 8);
        As[0][r][kq] = pa;
        Bs[0][rb][2*hb]   = pb0;
        Bs[0][rb][2*hb+1] = pb1;
    }
    __syncthreads();
    int nIt = K >> 5, cur = 0;
    for (int it = 0; it < nIt; ++it) {
        bool more = (it + 1 < nIt);
        short8 na, nb0, nb1;
        if (more) {
            int kk = (it + 1) * 32;
            na  = loadA(kk + kq * 8);
            nb0 = *(const short8*)(WT + brow + kk);
            nb1 = *(const short8*)(WT + brow + kk + 8);
        }
        short8 af = As[cur][w * 16 + ml][q];
        #pragma unroll
        for (int nt = 0; nt < 8; ++nt)
            acc[nt] = __builtin_amdgcn_mfma_f32_16x16x32_bf16(af, Bs[cur][nt*16 + ml][q],
                                                              acc[nt], 0, 0, 0);
        if (more) {
            As[cur ^ 1][r][kq] = na;
            Bs[cur ^ 1][rb][2*hb]   = nb0;
            Bs[cur ^ 1][rb][2*hb+1] = nb1;
            __syncthreads();
            cur ^= 1;
        }
    }
    float ov[8][4];
    #pragma unroll
    for (int nt = 0; nt < 8; ++nt) {
        int nn = n0 + nt * 16 + ml;
        float bv = ldS(bias, nn, pbf);
        #pragma unroll
        for (int reg = 0; reg < 4; ++reg) {
            float v = acc[nt][reg] + bv;
            v = v >= 0.f ? v : 0.01f * v;
            ov[nt][reg] = v;
            C[(size_t)(m0 + w * 16 + q * 4 + reg) * N + nn] = f2bf(v);
        }
    }
    if (statout) {
        #pragma unroll
        for (int reg = 0; reg < 4; ++reg) {
            float sv = 0.f, qv = 0.f;
            #pragma unroll
            for (int nt = 0; nt < 8; ++nt) {
                sv += ov[nt][reg];
                qv += ov[nt][reg] * ov[nt][reg];
            }
            #pragma unroll
            for (int mk = 1; mk < 16; mk <<= 1) {
                sv += __shfl_xor(sv, mk, 64);
                qv += __shfl_xor(qv, mk, 64);
            }
            if (ml == 0) {
                int row = m0 + w * 16 + q * 4 + reg;
                size_t base = ((size_t)blockIdx.y * M + row) * 2;
                statout[base]     = sv;
                statout[base + 1] = qv;
            }
        }
    }
}

// ---- gemm3 (x2 @ aw1, N=64) dbuf + fused LN(64)+attn-logit epilogue ----
__global__ __launch_bounds__(256) void gemm3_attn_k(const u16* __restrict__ Ap,
        const float2* __restrict__ statin, const void* __restrict__ g,
        const void* __restrict__ bta, const u16* __restrict__ WT,
        const void* __restrict__ bias,
        const void* __restrict__ alng, const void* __restrict__ alnb,
        const void* __restrict__ aw2, const void* __restrict__ ab2,
        const int* __restrict__ mask, float* __restrict__ lg,
        const u32* __restrict__ probe) {
    __shared__ short8 As[2][64][5];
    __shared__ short8 Bs[2][64][5];
    __shared__ float at[64][65];
    __shared__ float w2s[512];
    __shared__ float b2s[8];
    __shared__ float gs[64], bs[64];
    bool pbf = (probe[0] == BF16_ONES_PAIR);
    const int K = 256;
    int t = threadIdx.x;
    int m0 = blockIdx.x * 64;
    int r = t >> 2, kq = t & 3;
    int l = t & 63, w = t >> 6;
    int q = l >> 4, ml = l & 15;
    float4v acc[4];
    #pragma unroll
    for (int nt = 0; nt < 4; ++nt)
        #pragma unroll
        for (int i = 0; i < 4; ++i) acc[nt][i] = 0.f;
    float2 s0 = statin[m0 + r];
    float2 s1 = statin[M_ + m0 + r];
    float ssum = s0.x + s1.x, ssq = s0.y + s1.y;
    float stm = ssum * (1.f / K);
    float str = rsqrtf(ssq * (1.f / K) - stm * stm + 1e-6f);
    const size_t arow = (size_t)(m0 + r) * K;
    const size_t brow = (size_t)r * K;
    auto loadA = [&](int kk) -> short8 {
        f8 a  = ld8(Ap, arow + kk, true);
        f8 gg = ld8(g, kk, pbf);
        f8 bb = ld8(bta, kk, pbf);
        short8 pa;
        #pragma unroll
        for (int j = 0; j < 8; ++j)
            pa[j] = (short)f2bf((a.v[j] - stm) * str * gg.v[j] + bb.v[j]);
        return pa;
    };
    {
        short8 pa = loadA(kq * 8);
        short8 pb = *(const short8*)(WT + brow + kq * 8);
        As[0][r][kq] = pa;
        Bs[0][r][kq] = pb;
    }
    __syncthreads();
    int cur = 0;
    #pragma unroll
    for (int it = 0; it < 8; ++it) {
        bool more = (it < 7);
        short8 na, nb;
        if (more) {
            int kk = (it + 1) * 32 + kq * 8;
            na = loadA(kk);
            nb = *(const short8*)(WT + brow + kk);
        }
        short8 af = As[cur][w * 16 + ml][q];
        #pragma unroll
        for (int nt = 0; nt < 4; ++nt)
            acc[nt] = __builtin_amdgcn_mfma_f32_16x16x32_bf16(af, Bs[cur][nt*16 + ml][q],
                                                              acc[nt], 0, 0, 0);
        if (more) {
            As[cur ^ 1][r][kq] = na;
            Bs[cur ^ 1][r][kq] = nb;
            __syncthreads();
            cur ^= 1;
        }
    }
    // stage attn params + output tile in LDS
    for (int i = t; i < 512; i += 256) w2s[i] = ldS(aw2, i, pbf);
    if (t < 8) b2s[t] = ldS(ab2, t, pbf);
    if (t < 64) { gs[t] = ldS(alng, t, pbf); bs[t] = ldS(alnb, t, pbf); }
    #pragma unroll
    for (int nt = 0; nt < 4; ++nt) {
        int nn = nt * 16 + ml;
        float bv = ldS(bias, nn, pbf);
        #pragma unroll
        for (int reg = 0; reg < 4; ++reg) {
            float v = acc[nt][reg] + bv;
            v = v >= 0.f ? v : 0.01f * v;
            at[w * 16 + q * 4 + reg][nn] = v;
        }
    }
    __syncthreads();
    // per-row LN(64) + 8-head logits: 4 lanes per row, 16 cols each
    int row = t >> 2, s4 = t & 3;
    float av[16];
    float sum = 0.f, sq = 0.f;
    #pragma unroll
    for (int j = 0; j < 16; ++j) {
        float v = at[row][s4 * 16 + j];
        av[j] = v; sum += v; sq += v * v;
    }
    sum += __shfl_xor(sum, 1, 64); sum += __shfl_xor(sum, 2, 64);
    sq  += __shfl_xor(sq, 1, 64);  sq  += __shfl_xor(sq, 2, 64);
    float mr = sum * (1.f / 64);
    float rr = rsqrtf(sq * (1.f / 64) - mr * mr + 1e-6f);
    float val[16];
    #pragma unroll
    for (int j = 0; j < 16; ++j)
        val[j] = (av[j] - mr) * rr * gs[s4 * 16 + j] + bs[s4 * 16 + j];
    float hv[8];
    #pragma unroll
    for (int h = 0; h < 8; ++h) {
        float p = 0.f;
        #pragma unroll
        for (int j = 0; j < 16; ++j) p += val[j] * w2s[(s4 * 16 + j) * 8 + h];
        p += __shfl_xor(p, 1, 64);
        p += __shfl_xor(p, 2, 64);
        hv[h] = p + b2s[h];
    }
    if (s4 == 0) {
        int gr = m0 + row;
        bool mz = (mask[gr] == 0);
        int bb_ = gr >> 10, ll = gr & 1023;
        #pragma unroll
        for (int h = 0; h < 8; ++h) {
            float v = mz ? -1e9f : hv[h];
            lg[((size_t)bb_ * NH_ + h) * L_ + ll] = v;
        }
    }
}

// ---- fused softmax(L) + rstd-fold + pooling + LN2-affine: one block per (b,h) ----
__global__ __launch_bounds__(1024) void attnpool_k(const float* __restrict__ lg,
        const float2* __restrict__ st2, const u16* __restrict__ x2,
        const void* __restrict__ g, const void* __restrict__ b,
        float* __restrict__ hp, const u32* __restrict__ probe) {
    __shared__ float aw_s[1024];
    __shared__ float part[16][256];
    __shared__ float sh[16];
    bool pbf = (probe[0] == BF16_ONES_PAIR);
    int bh = blockIdx.x, t = threadIdx.x;
    int bb = bh >> 3;
    float v = lg[(size_t)bh * L_ + t];
    float mx = blk_max(v, sh);
    float e = expf(v - mx);
    float s = blk_sum(e, sh);
    float inv = 1.f / s;
    int sidx = (bb << 10) + t;
    float2 sa = st2[sidx];
    float2 sb = st2[8192 + sidx];
    float ssum = sa.x + sb.x, ssq = sa.y + sb.y;
    float m = ssum * (1.f / 256);
    float r = rsqrtf(ssq * (1.f / 256) - m * m + 1e-6f);
    float aw = e * inv * r;
    aw_s[t] = aw;
    float c1 = blk_sum(aw * m, sh);   // barrier inside makes aw_s visible
    int chunk = t >> 6, d0 = (t & 63) * 4;
    const u16* xb = x2 + ((size_t)(bb << 10) + chunk * 64) * 256;
    const float* awc = aw_s + chunk * 64;
    float a0 = 0.f, a1 = 0.f, a2 = 0.f, a3 = 0.f;
    #pragma unroll 8
    for (int i = 0; i < 64; ++i) {
        uint2 u = *(const uint2*)(xb + (size_t)i * 256 + d0);
        float wv = awc[i];
        a0 += wv * bf2f(u.x & 0xffff);
        a1 += wv * bf2f(u.x >> 16);
        a2 += wv * bf2f(u.y & 0xffff);
        a3 += wv * bf2f(u.y >> 16);
    }
    *(float4*)&part[chunk][d0] = make_float4(a0, a1, a2, a3);
    __syncthreads();
    if (t < 256) {
        float S = 0.f;
        #pragma unroll
        for (int c = 0; c < 16; ++c) S += part[c][t];
        hp[(size_t)bh * 256 + t] = (S - c1) * ldS(g, t, pbf) + ldS(b, t, pbf);
    }
}

// ---- split-K GEMV: LDS-staged h, 2 cols/thread, 32-deep batched loads,
//      partial-sum stores (NO atomics): part[chunk][r][c] ----
template<int KC>
__global__ __launch_bounds__(256) void gemv_ilp_part_k(const float* __restrict__ hv,
        const void* __restrict__ W, float* __restrict__ part, int K, int N,
        const u32* __restrict__ probe) {
    __shared__ float hs[8 * KC];
    bool bf = (probe[0] == BF16_ONES_PAIR);
    int t = threadIdx.x;
    int kb = blockIdx.y * KC;
    for (int i = t; i < 8 * KC; i += 256) {
        int r = i / KC, k = i & (KC - 1);
        hs[i] = hv[(size_t)r * K + kb + k];
    }
    __syncthreads();
    int c0 = (blockIdx.x * 256 + t) * 2;
    if (c0 >= N) return;
    float a[8][2] = {};
    if (bf) {
        const u16* Wp = (const u16*)W;
        #pragma unroll
        for (int h = 0; h < KC / 32; ++h) {
            u32 wr[32];
            #pragma unroll
            for (int i = 0; i < 32; ++i)
                wr[i] = *(const u32*)(Wp + (size_t)(kb + h * 32 + i) * N + c0);
            #pragma unroll
            for (int i = 0; i < 32; ++i) {
                float w0 = bf2f(wr[i] & 0xffff), w1 = bf2f(wr[i] >> 16);
                #pragma unroll
                for (int r = 0; r < 8; ++r) {
                    float hh = hs[r * KC + h * 32 + i];
                    a[r][0] += hh * w0; a[r][1] += hh * w1;
                }
            }
        }
    } else {
        const float* Wp = (const float*)W;
        #pragma unroll
        for (int h = 0; h < KC / 16; ++h) {
            float2 wr[16];
            #pragma unroll
            for (int i = 0; i < 16; ++i)
                wr[i] = *(const float2*)(Wp + (size_t)(kb + h * 16 + i) * N + c0);
            #pragma unroll
            for (int i = 0; i < 16; ++i) {
                #pragma unroll
                for (int r = 0; r < 8; ++r) {
                    float hh = hs[r * KC + h * 16 + i];
                    a[r][0] += hh * wr[i].x; a[r][1] += hh * wr[i].y;
                }
            }
        }
    }
    float* dst = part + ((size_t)blockIdx.y * 8) * N + c0;
    bool ok1 = (c0 + 1 < N);
    #pragma unroll
    for (int r = 0; r < 8; ++r) {
        if (ok1) *(float2*)(dst + (size_t)r * N) = make_float2(a[r][0], a[r][1]);
        else dst[(size_t)r * N] = a[r][0];
    }
}

// ---- combine 32 partials (explicit ILP tree) + bias + leaky + LN over 2048 cols ----
__global__ __launch_bounds__(1024) void out_ln_k(const float* __restrict__ part,
        float* __restrict__ h, const void* __restrict__ bias,
        const void* __restrict__ g, const void* __restrict__ b,
        const u32* __restrict__ probe) {
    __shared__ float sh[16];
    bool bf = (probe[0] == BF16_ONES_PAIR);
    int row = blockIdx.x, t = threadIdx.x;
    float v[2];
    float s = 0.f, q = 0.f;
    #pragma unroll
    for (int i = 0; i < 2; ++i) {
        int c = t + i * 1024;
        float pv[NCH];
        #pragma unroll
        for (int ch = 0; ch < NCH; ++ch)
            pv[ch] = part[((size_t)ch * 8 + row) * OD_ + c];
        #pragma unroll
        for (int st = NCH / 2; st >= 1; st >>= 1)
            #pragma unroll
            for (int j = 0; j < NCH; ++j)
                if (j < st) pv[j] += pv[j + st];
        float x = ldS(bias, c, bf) + pv[0];
        x = x >= 0.f ? x : 0.01f * x;
        v[i] = x; s += x; q += x * x;
    }
    s = blk_sum(s, sh) * (1.f / OD_);
    q = blk_sum(q, sh) * (1.f / OD_);
    float rstd = rsqrtf(q - s * s + 1e-6f);
    #pragma unroll
    for (int i = 0; i < 2; ++i) {
        int c = t + i * 1024;
        h[(size_t)row * OD_ + c] = (v[i] - s) * rstd * ldS(g, c, bf) + ldS(b, c, bf);
    }
}

// ---- combine 32 partials (row-parallel, explicit ILP tree) + bias + sigmoid + zero ----
__global__ __launch_bounds__(256) void sigmoid_t_k(const float* __restrict__ part,
        const void* __restrict__ bias, float* __restrict__ pt,
        float* __restrict__ out, const u32* __restrict__ probe) {
    bool bf = (probe[0] == BF16_ONES_PAIR);
    int c = blockIdx.x * 256 + threadIdx.x;
    int r = blockIdx.y;
    if (c >= LBL_) return;
    float pv[NCH];
    #pragma unroll
    for (int ch = 0; ch < NCH; ++ch)
        pv[ch] = part[((size_t)ch * 8 + r) * LBL_ + c];
    #pragma unroll
    for (int st = NCH / 2; st >= 1; st >>= 1)
        #pragma unroll
        for (int j = 0; j < NCH; ++j)
            if (j < st) pv[j] += pv[j + st];
    float v = ldS(bias, c, bf) + pv[0];
    pt[(size_t)c * 8 + r] = 1.f / (1.f + expf(-v));
    out[(size_t)r * LBL_ + c] = 0.f;
}

// ---- per-nonzero hit: LDS max over 8 batches ----
__device__ __forceinline__ void mp_hit(u32 idx, float cmv,
        const float* __restrict__ pt, int* smax, u32 rowBase) {
    u32 i = idx / LBL_;
    u32 j = idx - i * LBL_;
    const float4* pj = (const float4*)(pt + (size_t)j * 8);
    float4 pa = pj[0], pb = pj[1];
    int base = (int)(i - rowBase) * 8;
    atomicMax(&smax[base + 0], __float_as_int(pa.x * cmv));
    atomicMax(&smax[base + 1], __float_as_int(pa.y * cmv));
    atomicMax(&smax[base + 2], __float_as_int(pa.z * cmv));
    atomicMax(&smax[base + 3], __float_as_int(pa.w * cmv));
    atomicMax(&smax[base + 4], __float_as_int(pb.x * cmv));
    atomicMax(&smax[base + 5], __float_as_int(pb.y * cmv));
    atomicMax(&smax[base + 6], __float_as_int(pb.z * cmv));
    atomicMax(&smax[base + 7], __float_as_int(pb.w * cmv));
}

// ---- GO max-product: block-owned CM ranges, LDS row-max, few global atomics ----
__global__ __launch_bounds__(256) void maxprod3_k(const float* __restrict__ pt,
        const void* __restrict__ CM, float* __restrict__ out,
        const u32* __restrict__ probe) {
    __shared__ int smax[6 * 8];
    bool bf = (probe[0] == BF16_ONES_PAIR);
    int t = threadIdx.x;
    size_t blockStart = (size_t)blockIdx.x * MP_EPB;
    u32 rowBase = (u32)(blockStart / LBL_);
    for (int i = t; i < 48; i += 256) smax[i] = 0;
    __syncthreads();
    if (bf) {
        const u16* cm = (const u16*)CM;
        uint4 ch[8];
        size_t i0[8];
        #pragma unroll
        for (int u = 0; u < 8; ++u) {
            size_t idx0 = blockStart + ((size_t)u * 256 + t) * 8;
            i0[u] = idx0;
            ch[u] = (idx0 + 8 <= NCM) ? *(const uint4*)(cm + idx0)
                                      : make_uint4(0, 0, 0, 0);
        }
        #pragma unroll
        for (int u = 0; u < 8; ++u) {
            size_t idx0 = i0[u];
            if (idx0 + 8 <= NCM) {
                uint4 c4 = ch[u];
                if ((c4.x | c4.y | c4.z | c4.w) == 0) continue;
                u32 hw[4] = {c4.x, c4.y, c4.z, c4.w};
                #pragma unroll
                for (int d = 0; d < 4; ++d) {
                    u32 lo = hw[d] & 0xffff, hi = hw[d] >> 16;
                    if (lo) mp_hit((u32)idx0 + d*2,     bf2f(lo), pt, smax, rowBase);
                    if (hi) mp_hit((u32)idx0 + d*2 + 1, bf2f(hi), pt, smax, rowBase);
                }
            } else if (idx0 < NCM) {
                for (u32 e = 0; e < (u32)(NCM - idx0); ++e) {
                    u16 h = cm[idx0 + e];
                    if (h) mp_hit((u32)idx0 + e, bf2f(h), pt, smax, rowBase);
                }
            }
        }
    } else {
        const float* cm = (const float*)CM;
        #pragma unroll
        for (int u = 0; u < 16; ++u) {
            size_t idx0 = blockStart + ((size_t)u * 256 + t) * 4;
            if (idx0 >= NCM) continue;
            float v[4];
            if (idx0 + 4 <= NCM) {
                float4 f = *(const float4*)(cm + idx0);
                v[0] = f.x; v[1] = f.y; v[2] = f.z; v[3] = f.w;
            } else {
                v[0] = v[1] = v[2] = v[3] = 0.f;
                for (u32 e = 0; e < (u32)(NCM - idx0); ++e) v[e] = cm[idx0 + e];
            }
            if (v[0] == 0.f && v[1] == 0.f && v[2] == 0.f && v[3] == 0.f) continue;
            #pragma unroll
            for (int e = 0; e < 4; ++e)
                if (v[e] != 0.f) mp_hit((u32)idx0 + e, v[e], pt, smax, rowBase);
        }
    }
    __syncthreads();
    size_t lastIdx = blockStart + MP_EPB - 1;
    if (lastIdx >= NCM) lastIdx = NCM - 1;
    int nrows = (int)((u32)(lastIdx / LBL_) - rowBase) + 1;
    for (int s = t; s < nrows * 8; s += 256) {
        int v = smax[s];
        if (v != 0) {
            int rr = s >> 3, b = s & 7;
            atomicMax((int*)(out + (size_t)b * LBL_ + rowBase + rr), v);
        }
    }
}

extern "C" void kernel_launch(void* const* d_in, const int* in_sizes, int n_in,
                              void* d_out, int out_size, void* d_ws, size_t ws_size,
                              hipStream_t stream) {
    const void* hv   = d_in[0];
    const int* mask  = (const int*)d_in[1];
    const void* ln0g = d_in[2];
    const void* ln0b = d_in[3];
    const void* w_in = d_in[4];
    const void* b_in = d_in[5];
    const void* ln1g = d_in[6];
    const void* ln1b = d_in[7];
    const void* w_h  = d_in[8];
    const void* b_h  = d_in[9];
    const void* ln2g = d_in[10];
    const void* ln2b = d_in[11];
    const void* aw1  = d_in[12];
    const void* ab1  = d_in[13];
    const void* alng = d_in[14];
    const void* alnb = d_in[15];
    const void* aw2  = d_in[16];
    const void* ab2  = d_in[17];
    const void* ow1  = d_in[18];
    const void* ob1  = d_in[19];
    const void* olng = d_in[20];
    const void* olnb = d_in[21];
    const void* ow2  = d_in[22];
    const void* ob2  = d_in[23];
    const void* CM   = d_in[24];
    const u32* probe = (const u32*)ln0g;
    float* out = (float*)d_out;

    float* f = (float*)d_ws;
    float2* st1 = (float2*)f;                    // [2][8192] float2 = 32768 floats
    float2* st2 = st1 + 16384;                   // [2][8192] float2 = 32768 floats
    float* lg    = f + 65536;                    // 65536  [8,8,1024]
    float* hp    = lg + 65536;                   // 16384
    float* ha    = hp + 16384;                   // 16384  (LN'd h)
    float* part1 = ha + 16384;                   // 32*8*2048 = 524288
    float* part2 = part1 + 524288;               // 32*8*4766 = 1220096
    float* pt    = part2 + 1220096;              // 38128  (transposed sigmoid)
    u16* x0  = (u16*)(pt + 38128);               // 8192*1024
    u16* x1  = x0 + 8388608;                     // 8192*256
    u16* x2  = x1 + 2097152;                     // 8192*256
    u16* wt1 = x2 + 2097152;                     // 256*1024
    u16* wt2 = wt1 + 262144;                     // 256*256
    u16* wt3 = wt2 + 65536;                      // 64*256

    // 1: LN0 (wave-per-row) + transposes (no stat zeroing needed now)
    prep_k<<<M_/4 + 84, 256, 0, stream>>>(hv, ln0g, ln0b, x0,
                                          w_in, wt1, w_h, wt2, aw1, wt3, probe);
    // 2-3: trunk GEMMs, 64x128 tiles, plain partial-stat stores
    gemm_mfma<<<dim3(M_/64, 2), 256, 0, stream>>>(x0, 2, nullptr, nullptr, nullptr,
                                                  wt1, b_in, x1, (float*)st1,
                                                  M_, H_, F_, probe);
    gemm_mfma<<<dim3(M_/64, 2), 256, 0, stream>>>(x1, 1, st1, ln1g, ln1b,
                                                  wt2, b_h, x2, (float*)st2,
                                                  M_, H_, H_, probe);
    // 4: gemm3 + fused LN(64) + attn logits
    gemm3_attn_k<<<M_/64, 256, 0, stream>>>(x2, st2, ln2g, ln2b, wt3, ab1,
                                            alng, alnb, aw2, ab2, mask, lg, probe);
    // 5: fused softmax + pooling + LN2-affine
    attnpool_k<<<B_*NH_, 1024, 0, stream>>>(lg, st2, x2, ln2g, ln2b, hp, probe);
    // 6-9: output block — gemv partials (KC=64, 32 chunks) + 32-deep ILP combines
    gemv_ilp_part_k<64><<<dim3(OD_/512, NCH), 256, 0, stream>>>(hp, ow1, part1,
                                                                OD_, OD_, probe);
    out_ln_k<<<B_, 1024, 0, stream>>>(part1, ha, ob1, olng, olnb, probe);
    gemv_ilp_part_k<64><<<dim3((LBL_+511)/512, NCH), 256, 0, stream>>>(ha, ow2, part2,
                                                                       OD_, LBL_, probe);
    sigmoid_t_k<<<dim3((LBL_+255)/256, 8), 256, 0, stream>>>(part2, ob2, pt, out, probe);
    // 10: GO max-product
    maxprod3_k<<<MP_NB, 256, 0, stream>>>(pt, CM, out, probe);
}

// Round 9
// 331.213 us; speedup vs baseline: 1.0304x; 1.0304x over previous
//
#include <hip/hip_runtime.h>
#include <hip/hip_bf16.h>
#include <cstdint>

#define B_   8
#define L_   1024
#define F_   1024
#define H_   256
#define NH_  8
#define LBL_ 4766
#define M_   (B_*L_)    // 8192
#define OD_  (NH_*H_)   // 2048
#define NCM  (LBL_*LBL_)     // 22714756
#define MP_EPB 16384
#define MP_NB  ((NCM + MP_EPB - 1) / MP_EPB)   // 1387
#define NCH  32          // k-chunks per GEMV (K=2048 / KC=64)

typedef unsigned short u16;
typedef unsigned int   u32;
typedef __attribute__((ext_vector_type(8))) short short8;
typedef __attribute__((ext_vector_type(4))) float float4v;

#define BF16_ONES_PAIR 0x3f803f80u

__device__ __forceinline__ float bf2f(u32 u) { return __uint_as_float(u << 16); }
__device__ __forceinline__ u16 f2bf(float f) {
    u32 u = __float_as_uint(f);
    u32 r = 0x7fffu + ((u >> 16) & 1u);
    return (u16)((u + r) >> 16);
}

struct f8 { float v[8]; };

__device__ __forceinline__ float ldS(const void* p, size_t i, bool bf) {
    return bf ? bf2f(((const u16*)p)[i]) : ((const float*)p)[i];
}
__device__ __forceinline__ float4 ld4(const void* p, size_t i, bool bf) {
    if (bf) {
        uint2 u = *(const uint2*)((const u16*)p + i);
        return make_float4(bf2f(u.x & 0xffff), bf2f(u.x >> 16),
                           bf2f(u.y & 0xffff), bf2f(u.y >> 16));
    }
    return *(const float4*)((const float*)p + i);
}
__device__ __forceinline__ f8 ld8(const void* p, size_t i, bool bf) {
    f8 r;
    if (bf) {
        uint4 u = *(const uint4*)((const u16*)p + i);
        r.v[0]=bf2f(u.x&0xffff); r.v[1]=bf2f(u.x>>16);
        r.v[2]=bf2f(u.y&0xffff); r.v[3]=bf2f(u.y>>16);
        r.v[4]=bf2f(u.z&0xffff); r.v[5]=bf2f(u.z>>16);
        r.v[6]=bf2f(u.w&0xffff); r.v[7]=bf2f(u.w>>16);
    } else {
        const float* q = (const float*)p + i;
        float4 a = *(const float4*)q, b = *(const float4*)(q+4);
        r.v[0]=a.x; r.v[1]=a.y; r.v[2]=a.z; r.v[3]=a.w;
        r.v[4]=b.x; r.v[5]=b.y; r.v[6]=b.z; r.v[7]=b.w;
    }
    return r;
}

__device__ __forceinline__ float wave_sum(float v) {
    #pragma unroll
    for (int m = 1; m < 64; m <<= 1) v += __shfl_xor(v, m, 64);
    return v;
}
__device__ __forceinline__ float wave_max(float v) {
    #pragma unroll
    for (int m = 1; m < 64; m <<= 1) v = fmaxf(v, __shfl_xor(v, m, 64));
    return v;
}
__device__ __forceinline__ float blk_sum(float v, float* sh) {
    v = wave_sum(v);
    int w = threadIdx.x >> 6, nw = blockDim.x >> 6;
    if ((threadIdx.x & 63) == 0) sh[w] = v;
    __syncthreads();
    float s = sh[0];
    for (int i = 1; i < nw; ++i) s += sh[i];
    __syncthreads();
    return s;
}
__device__ __forceinline__ float blk_max(float v, float* sh) {
    v = wave_max(v);
    int w = threadIdx.x >> 6, nw = blockDim.x >> 6;
    if ((threadIdx.x & 63) == 0) sh[w] = v;
    __syncthreads();
    float s = sh[0];
    for (int i = 1; i < nw; ++i) s = fmaxf(s, sh[i]);
    __syncthreads();
    return s;
}

// ---- fused prep: LN0 (wave-per-row, 4 rows/block) | 3 weight transposes ----
__global__ __launch_bounds__(256) void prep_k(const void* __restrict__ hv,
        const void* __restrict__ g0, const void* __restrict__ b0, u16* __restrict__ x0,
        const void* __restrict__ w_in, u16* __restrict__ wt1,
        const void* __restrict__ w_h,  u16* __restrict__ wt2,
        const void* __restrict__ aw1,  u16* __restrict__ wt3,
        const u32* __restrict__ probe) {
    __shared__ u16 tile[64][65];
    bool bf = (probe[0] == BF16_ONES_PAIR);
    int blk = blockIdx.x, t = threadIdx.x;
    if (blk < M_/4) {                      // LN0: one wave per row, no barriers
        int row = (blk << 2) + (t >> 6);
        int l = t & 63;
        size_t base = (size_t)row * F_;
        float4 vv[4];
        float s = 0.f, q = 0.f;
        #pragma unroll
        for (int j = 0; j < 4; ++j) {
            float4 v = ld4(hv, base + l * 4 + j * 256, bf);
            vv[j] = v;
            s += v.x + v.y + v.z + v.w;
            q += v.x*v.x + v.y*v.y + v.z*v.z + v.w*v.w;
        }
        s = wave_sum(s);
        q = wave_sum(q);
        float mean = s * (1.f / F_);
        float rstd = rsqrtf(q * (1.f / F_) - mean * mean + 1e-6f);
        #pragma unroll
        for (int j = 0; j < 4; ++j) {
            int off = l * 4 + j * 256;
            float4 gg = ld4(g0, off, bf);
            float4 bb = ld4(b0, off, bf);
            float4 v = vv[j];
            u32 o0 = f2bf((v.x - mean) * rstd * gg.x + bb.x)
                   | ((u32)f2bf((v.y - mean) * rstd * gg.y + bb.y) << 16);
            u32 o1 = f2bf((v.z - mean) * rstd * gg.z + bb.z)
                   | ((u32)f2bf((v.w - mean) * rstd * gg.w + bb.w) << 16);
            *(uint2*)(x0 + base + off) = make_uint2(o0, o1);
        }
        return;
    }
    blk -= M_/4;
    const void* W = nullptr; u16* WT = nullptr; int K = 0, N = 0, kt = 0, nt = 0;
    if (blk < 64)      { W = w_in; WT = wt1; K = F_; N = H_; kt = blk & 15; nt = blk >> 4; }
    else if (blk < 80) { int j = blk - 64; W = w_h; WT = wt2; K = H_; N = H_; kt = j & 3; nt = j >> 2; }
    else               { int j = blk - 80; W = aw1; WT = wt3; K = H_; N = 64; kt = j; nt = 0; }
    int kt0 = kt * 64, nt0 = nt * 64;
    int r = t >> 2, cq = (t & 3) * 16;
    #pragma unroll
    for (int j = 0; j < 4; ++j) {
        float4 v = ld4(W, (size_t)(kt0 + r) * N + nt0 + cq + j * 4, bf);
        tile[r][cq + j*4 + 0] = f2bf(v.x);
        tile[r][cq + j*4 + 1] = f2bf(v.y);
        tile[r][cq + j*4 + 2] = f2bf(v.z);
        tile[r][cq + j*4 + 3] = f2bf(v.w);
    }
    __syncthreads();
    #pragma unroll
    for (int j = 0; j < 4; ++j) {
        int k = cq + j * 4;
        u32 a0 = tile[k+0][r], a1 = tile[k+1][r], a2 = tile[k+2][r], a3 = tile[k+3][r];
        uint2 o; o.x = a0 | (a1 << 16); o.y = a2 | (a3 << 16);
        *(uint2*)(WT + (size_t)(nt0 + r) * K + kt0 + k) = o;
    }
}

// ---- MFMA bf16 GEMM, 64x64 tile, grid (M/64, 4), BK=64 dbuf (1 barrier / 64-K),
//      stats: plain partial stores st[4][M] (float2); statin summed over 4. ----
__global__ __launch_bounds__(256) void gemm_mfma(const u16* __restrict__ Ap, int amode,
        const float2* __restrict__ statin, const void* __restrict__ g,
        const void* __restrict__ bta, const u16* __restrict__ WT,
        const void* __restrict__ bias, u16* __restrict__ C,
        float* __restrict__ statout, int M, int N, int K,
        const u32* __restrict__ probe) {
    __shared__ short8 As[2][64][9];   // slots 0..7 used, 9th = bank pad
    __shared__ short8 Bs[2][64][9];
    bool pbf = (probe[0] == BF16_ONES_PAIR);
    int t = threadIdx.x;
    int m0 = blockIdx.x * 64, n0 = blockIdx.y * 64;
    int r = t >> 2, kq = t & 3;
    int l = t & 63, w = t >> 6;
    int q = l >> 4, ml = l & 15;
    float4v acc[4];
    #pragma unroll
    for (int nt = 0; nt < 4; ++nt)
        #pragma unroll
        for (int i = 0; i < 4; ++i) acc[nt][i] = 0.f;
    float stm = 0.f, str = 1.f;
    if (amode == 1) {
        float ssum = 0.f, ssq = 0.f;
        #pragma unroll
        for (int p = 0; p < 4; ++p) {
            float2 s = statin[(size_t)p * M + m0 + r];
            ssum += s.x; ssq += s.y;
        }
        float mm = ssum * (1.f / K);
        stm = mm;
        str = rsqrtf(ssq * (1.f / K) - mm * mm + 1e-6f);
    }
    const size_t arow = (size_t)(m0 + r) * K;
    const size_t brow = (size_t)(n0 + r) * K;
    auto loadA = [&](int kk) -> short8 {
        if (amode == 1) {
            f8 a  = ld8(Ap, arow + kk, true);
            f8 gg = ld8(g, kk, pbf);
            f8 bb = ld8(bta, kk, pbf);
            short8 pa;
            #pragma unroll
            for (int j = 0; j < 8; ++j)
                pa[j] = (short)f2bf((a.v[j] - stm) * str * gg.v[j] + bb.v[j]);
            return pa;
        }
        return *(const short8*)(Ap + arow + kk);
    };
    // prologue: stage K 0..63 into buffer 0 (each thread: slots kq and kq+4)
    {
        As[0][r][kq]     = loadA(kq * 8);
        As[0][r][kq + 4] = loadA(32 + kq * 8);
        Bs[0][r][kq]     = *(const short8*)(WT + brow + kq * 8);
        Bs[0][r][kq + 4] = *(const short8*)(WT + brow + 32 + kq * 8);
    }
    __syncthreads();
    int nIt = K >> 6, cur = 0;
    for (int it = 0; it < nIt; ++it) {
        bool more = (it + 1 < nIt);
        short8 na0, na1, nb0, nb1;
        if (more) {
            int kk = (it + 1) * 64;
            na0 = loadA(kk + kq * 8);
            na1 = loadA(kk + 32 + kq * 8);
            nb0 = *(const short8*)(WT + brow + kk + kq * 8);
            nb1 = *(const short8*)(WT + brow + kk + 32 + kq * 8);
        }
        #pragma unroll
        for (int ks = 0; ks < 2; ++ks) {
            short8 af = As[cur][w * 16 + ml][ks * 4 + q];
            #pragma unroll
            for (int nt = 0; nt < 4; ++nt)
                acc[nt] = __builtin_amdgcn_mfma_f32_16x16x32_bf16(
                              af, Bs[cur][nt*16 + ml][ks * 4 + q], acc[nt], 0, 0, 0);
        }
        if (more) {
            As[cur ^ 1][r][kq]     = na0;
            As[cur ^ 1][r][kq + 4] = na1;
            Bs[cur ^ 1][r][kq]     = nb0;
            Bs[cur ^ 1][r][kq + 4] = nb1;
            __syncthreads();
            cur ^= 1;
        }
    }
    float ov[4][4];
    #pragma unroll
    for (int nt = 0; nt < 4; ++nt) {
        int nn = n0 + nt * 16 + ml;
        float bv = ldS(bias, nn, pbf);
        #pragma unroll
        for (int reg = 0; reg < 4; ++reg) {
            float v = acc[nt][reg] + bv;
            v = v >= 0.f ? v : 0.01f * v;
            ov[nt][reg] = v;
            C[(size_t)(m0 + w * 16 + q * 4 + reg) * N + nn] = f2bf(v);
        }
    }
    if (statout) {
        #pragma unroll
        for (int reg = 0; reg < 4; ++reg) {
            float sv = ov[0][reg] + ov[1][reg] + ov[2][reg] + ov[3][reg];
            float qv = ov[0][reg]*ov[0][reg] + ov[1][reg]*ov[1][reg]
                     + ov[2][reg]*ov[2][reg] + ov[3][reg]*ov[3][reg];
            #pragma unroll
            for (int mk = 1; mk < 16; mk <<= 1) {
                sv += __shfl_xor(sv, mk, 64);
                qv += __shfl_xor(qv, mk, 64);
            }
            if (ml == 0) {
                int row = m0 + w * 16 + q * 4 + reg;
                *(float2*)&statout[((size_t)blockIdx.y * M + row) * 2] =
                    make_float2(sv, qv);
            }
        }
    }
}

// ---- gemm3 (x2 @ aw1, N=64) dbuf + fused LN(64)+attn-logit epilogue ----
__global__ __launch_bounds__(256) void gemm3_attn_k(const u16* __restrict__ Ap,
        const float2* __restrict__ statin, const void* __restrict__ g,
        const void* __restrict__ bta, const u16* __restrict__ WT,
        const void* __restrict__ bias,
        const void* __restrict__ alng, const void* __restrict__ alnb,
        const void* __restrict__ aw2, const void* __restrict__ ab2,
        const int* __restrict__ mask, float* __restrict__ lg,
        const u32* __restrict__ probe) {
    __shared__ short8 As[2][64][5];
    __shared__ short8 Bs[2][64][5];
    __shared__ float at[64][65];
    __shared__ float w2s[512];
    __shared__ float b2s[8];
    __shared__ float gs[64], bs[64];
    bool pbf = (probe[0] == BF16_ONES_PAIR);
    const int K = 256;
    int t = threadIdx.x;
    int m0 = blockIdx.x * 64;
    int r = t >> 2, kq = t & 3;
    int l = t & 63, w = t >> 6;
    int q = l >> 4, ml = l & 15;
    float4v acc[4];
    #pragma unroll
    for (int nt = 0; nt < 4; ++nt)
        #pragma unroll
        for (int i = 0; i < 4; ++i) acc[nt][i] = 0.f;
    float ssum = 0.f, ssq = 0.f;
    #pragma unroll
    for (int p = 0; p < 4; ++p) {
        float2 s = statin[(size_t)p * M_ + m0 + r];
        ssum += s.x; ssq += s.y;
    }
    float stm = ssum * (1.f / K);
    float str = rsqrtf(ssq * (1.f / K) - stm * stm + 1e-6f);
    const size_t arow = (size_t)(m0 + r) * K;
    const size_t brow = (size_t)r * K;
    auto loadA = [&](int kk) -> short8 {
        f8 a  = ld8(Ap, arow + kk, true);
        f8 gg = ld8(g, kk, pbf);
        f8 bb = ld8(bta, kk, pbf);
        short8 pa;
        #pragma unroll
        for (int j = 0; j < 8; ++j)
            pa[j] = (short)f2bf((a.v[j] - stm) * str * gg.v[j] + bb.v[j]);
        return pa;
    };
    {
        short8 pa = loadA(kq * 8);
        short8 pb = *(const short8*)(WT + brow + kq * 8);
        As[0][r][kq] = pa;
        Bs[0][r][kq] = pb;
    }
    __syncthreads();
    int cur = 0;
    #pragma unroll
    for (int it = 0; it < 8; ++it) {
        bool more = (it < 7);
        short8 na, nb;
        if (more) {
            int kk = (it + 1) * 32 + kq * 8;
            na = loadA(kk);
            nb = *(const short8*)(WT + brow + kk);
        }
        short8 af = As[cur][w * 16 + ml][q];
        #pragma unroll
        for (int nt = 0; nt < 4; ++nt)
            acc[nt] = __builtin_amdgcn_mfma_f32_16x16x32_bf16(af, Bs[cur][nt*16 + ml][q],
                                                              acc[nt], 0, 0, 0);
        if (more) {
            As[cur ^ 1][r][kq] = na;
            Bs[cur ^ 1][r][kq] = nb;
            __syncthreads();
            cur ^= 1;
        }
    }
    // stage attn params + output tile in LDS
    for (int i = t; i < 512; i += 256) w2s[i] = ldS(aw2, i, pbf);
    if (t < 8) b2s[t] = ldS(ab2, t, pbf);
    if (t < 64) { gs[t] = ldS(alng, t, pbf); bs[t] = ldS(alnb, t, pbf); }
    #pragma unroll
    for (int nt = 0; nt < 4; ++nt) {
        int nn = nt * 16 + ml;
        float bv = ldS(bias, nn, pbf);
        #pragma unroll
        for (int reg = 0; reg < 4; ++reg) {
            float v = acc[nt][reg] + bv;
            v = v >= 0.f ? v : 0.01f * v;
            at[w * 16 + q * 4 + reg][nn] = v;
        }
    }
    __syncthreads();
    // per-row LN(64) + 8-head logits: 4 lanes per row, 16 cols each
    int row = t >> 2, s4 = t & 3;
    float av[16];
    float sum = 0.f, sq = 0.f;
    #pragma unroll
    for (int j = 0; j < 16; ++j) {
        float v = at[row][s4 * 16 + j];
        av[j] = v; sum += v; sq += v * v;
    }
    sum += __shfl_xor(sum, 1, 64); sum += __shfl_xor(sum, 2, 64);
    sq  += __shfl_xor(sq, 1, 64);  sq  += __shfl_xor(sq, 2, 64);
    float mr = sum * (1.f / 64);
    float rr = rsqrtf(sq * (1.f / 64) - mr * mr + 1e-6f);
    float val[16];
    #pragma unroll
    for (int j = 0; j < 16; ++j)
        val[j] = (av[j] - mr) * rr * gs[s4 * 16 + j] + bs[s4 * 16 + j];
    float hv[8];
    #pragma unroll
    for (int h = 0; h < 8; ++h) {
        float p = 0.f;
        #pragma unroll
        for (int j = 0; j < 16; ++j) p += val[j] * w2s[(s4 * 16 + j) * 8 + h];
        p += __shfl_xor(p, 1, 64);
        p += __shfl_xor(p, 2, 64);
        hv[h] = p + b2s[h];
    }
    if (s4 == 0) {
        int gr = m0 + row;
        bool mz = (mask[gr] == 0);
        int bb_ = gr >> 10, ll = gr & 1023;
        #pragma unroll
        for (int h = 0; h < 8; ++h) {
            float v = mz ? -1e9f : hv[h];
            lg[((size_t)bb_ * NH_ + h) * L_ + ll] = v;
        }
    }
}

// ---- fused softmax(L) + rstd-fold + pooling + LN2-affine: one block per (b,h) ----
__global__ __launch_bounds__(1024) void attnpool_k(const float* __restrict__ lg,
        const float2* __restrict__ st2, const u16* __restrict__ x2,
        const void* __restrict__ g, const void* __restrict__ b,
        float* __restrict__ hp, const u32* __restrict__ probe) {
    __shared__ float aw_s[1024];
    __shared__ float part[16][256];
    __shared__ float sh[16];
    bool pbf = (probe[0] == BF16_ONES_PAIR);
    int bh = blockIdx.x, t = threadIdx.x;
    int bb = bh >> 3;
    float v = lg[(size_t)bh * L_ + t];
    float mx = blk_max(v, sh);
    float e = expf(v - mx);
    float s = blk_sum(e, sh);
    float inv = 1.f / s;
    int sidx = (bb << 10) + t;
    float ssum = 0.f, ssq = 0.f;
    #pragma unroll
    for (int p = 0; p < 4; ++p) {
        float2 sp = st2[(size_t)p * 8192 + sidx];
        ssum += sp.x; ssq += sp.y;
    }
    float m = ssum * (1.f / 256);
    float r = rsqrtf(ssq * (1.f / 256) - m * m + 1e-6f);
    float aw = e * inv * r;
    aw_s[t] = aw;
    float c1 = blk_sum(aw * m, sh);   // barrier inside makes aw_s visible
    int chunk = t >> 6, d0 = (t & 63) * 4;
    const u16* xb = x2 + ((size_t)(bb << 10) + chunk * 64) * 256;
    const float* awc = aw_s + chunk * 64;
    float a0 = 0.f, a1 = 0.f, a2 = 0.f, a3 = 0.f;
    #pragma unroll 8
    for (int i = 0; i < 64; ++i) {
        uint2 u = *(const uint2*)(xb + (size_t)i * 256 + d0);
        float wv = awc[i];
        a0 += wv * bf2f(u.x & 0xffff);
        a1 += wv * bf2f(u.x >> 16);
        a2 += wv * bf2f(u.y & 0xffff);
        a3 += wv * bf2f(u.y >> 16);
    }
    *(float4*)&part[chunk][d0] = make_float4(a0, a1, a2, a3);
    __syncthreads();
    if (t < 256) {
        float S = 0.f;
        #pragma unroll
        for (int c = 0; c < 16; ++c) S += part[c][t];
        hp[(size_t)bh * 256 + t] = (S - c1) * ldS(g, t, pbf) + ldS(b, t, pbf);
    }
}

// ---- split-K GEMV: LDS-staged h, 2 cols/thread, 32-deep batched loads,
//      partial-sum stores (NO atomics): part[chunk][r][c] ----
template<int KC>
__global__ __launch_bounds__(256) void gemv_ilp_part_k(const float* __restrict__ hv,
        const void* __restrict__ W, float* __restrict__ part, int K, int N,
        const u32* __restrict__ probe) {
    __shared__ float hs[8 * KC];
    bool bf = (probe[0] == BF16_ONES_PAIR);
    int t = threadIdx.x;
    int kb = blockIdx.y * KC;
    for (int i = t; i < 8 * KC; i += 256) {
        int r = i / KC, k = i & (KC - 1);
        hs[i] = hv[(size_t)r * K + kb + k];
    }
    __syncthreads();
    int c0 = (blockIdx.x * 256 + t) * 2;
    if (c0 >= N) return;
    float a[8][2] = {};
    if (bf) {
        const u16* Wp = (const u16*)W;
        #pragma unroll
        for (int h = 0; h < KC / 32; ++h) {
            u32 wr[32];
            #pragma unroll
            for (int i = 0; i < 32; ++i)
                wr[i] = *(const u32*)(Wp + (size_t)(kb + h * 32 + i) * N + c0);
            #pragma unroll
            for (int i = 0; i < 32; ++i) {
                float w0 = bf2f(wr[i] & 0xffff), w1 = bf2f(wr[i] >> 16);
                #pragma unroll
                for (int r = 0; r < 8; ++r) {
                    float hh = hs[r * KC + h * 32 + i];
                    a[r][0] += hh * w0; a[r][1] += hh * w1;
                }
            }
        }
    } else {
        const float* Wp = (const float*)W;
        #pragma unroll
        for (int h = 0; h < KC / 16; ++h) {
            float2 wr[16];
            #pragma unroll
            for (int i = 0; i < 16; ++i)
                wr[i] = *(const float2*)(Wp + (size_t)(kb + h * 16 + i) * N + c0);
            #pragma unroll
            for (int i = 0; i < 16; ++i) {
                #pragma unroll
                for (int r = 0; r < 8; ++r) {
                    float hh = hs[r * KC + h * 16 + i];
                    a[r][0] += hh * wr[i].x; a[r][1] += hh * wr[i].y;
                }
            }
        }
    }
    float* dst = part + ((size_t)blockIdx.y * 8) * N + c0;
    bool ok1 = (c0 + 1 < N);
    #pragma unroll
    for (int r = 0; r < 8; ++r) {
        if (ok1) *(float2*)(dst + (size_t)r * N) = make_float2(a[r][0], a[r][1]);
        else dst[(size_t)r * N] = a[r][0];
    }
}

// ---- combine 32 partials (explicit ILP tree) + bias + leaky + LN over 2048 cols ----
__global__ __launch_bounds__(1024) void out_ln_k(const float* __restrict__ part,
        float* __restrict__ h, const void* __restrict__ bias,
        const void* __restrict__ g, const void* __restrict__ b,
        const u32* __restrict__ probe) {
    __shared__ float sh[16];
    bool bf = (probe[0] == BF16_ONES_PAIR);
    int row = blockIdx.x, t = threadIdx.x;
    float v[2];
    float s = 0.f, q = 0.f;
    #pragma unroll
    for (int i = 0; i < 2; ++i) {
        int c = t + i * 1024;
        float pv[NCH];
        #pragma unroll
        for (int ch = 0; ch < NCH; ++ch)
            pv[ch] = part[((size_t)ch * 8 + row) * OD_ + c];
        #pragma unroll
        for (int st = NCH / 2; st >= 1; st >>= 1)
            #pragma unroll
            for (int j = 0; j < NCH; ++j)
                if (j < st) pv[j] += pv[j + st];
        float x = ldS(bias, c, bf) + pv[0];
        x = x >= 0.f ? x : 0.01f * x;
        v[i] = x; s += x; q += x * x;
    }
    s = blk_sum(s, sh) * (1.f / OD_);
    q = blk_sum(q, sh) * (1.f / OD_);
    float rstd = rsqrtf(q - s * s + 1e-6f);
    #pragma unroll
    for (int i = 0; i < 2; ++i) {
        int c = t + i * 1024;
        h[(size_t)row * OD_ + c] = (v[i] - s) * rstd * ldS(g, c, bf) + ldS(b, c, bf);
    }
}

// ---- combine 32 partials (row-parallel, explicit ILP tree) + bias + sigmoid + zero ----
__global__ __launch_bounds__(256) void sigmoid_t_k(const float* __restrict__ part,
        const void* __restrict__ bias, float* __restrict__ pt,
        float* __restrict__ out, const u32* __restrict__ probe) {
    bool bf = (probe[0] == BF16_ONES_PAIR);
    int c = blockIdx.x * 256 + threadIdx.x;
    int r = blockIdx.y;
    if (c >= LBL_) return;
    float pv[NCH];
    #pragma unroll
    for (int ch = 0; ch < NCH; ++ch)
        pv[ch] = part[((size_t)ch * 8 + r) * LBL_ + c];
    #pragma unroll
    for (int st = NCH / 2; st >= 1; st >>= 1)
        #pragma unroll
        for (int j = 0; j < NCH; ++j)
            if (j < st) pv[j] += pv[j + st];
    float v = ldS(bias, c, bf) + pv[0];
    pt[(size_t)c * 8 + r] = 1.f / (1.f + expf(-v));
    out[(size_t)r * LBL_ + c] = 0.f;
}

// ---- per-nonzero hit: LDS max over 8 batches ----
__device__ __forceinline__ void mp_hit(u32 idx, float cmv,
        const float* __restrict__ pt, int* smax, u32 rowBase) {
    u32 i = idx / LBL_;
    u32 j = idx - i * LBL_;
    const float4* pj = (const float4*)(pt + (size_t)j * 8);
    float4 pa = pj[0], pb = pj[1];
    int base = (int)(i - rowBase) * 8;
    atomicMax(&smax[base + 0], __float_as_int(pa.x * cmv));
    atomicMax(&smax[base + 1], __float_as_int(pa.y * cmv));
    atomicMax(&smax[base + 2], __float_as_int(pa.z * cmv));
    atomicMax(&smax[base + 3], __float_as_int(pa.w * cmv));
    atomicMax(&smax[base + 4], __float_as_int(pb.x * cmv));
    atomicMax(&smax[base + 5], __float_as_int(pb.y * cmv));
    atomicMax(&smax[base + 6], __float_as_int(pb.z * cmv));
    atomicMax(&smax[base + 7], __float_as_int(pb.w * cmv));
}

// ---- GO max-product: block-owned CM ranges, LDS row-max, few global atomics ----
__global__ __launch_bounds__(256) void maxprod3_k(const float* __restrict__ pt,
        const void* __restrict__ CM, float* __restrict__ out,
        const u32* __restrict__ probe) {
    __shared__ int smax[6 * 8];
    bool bf = (probe[0] == BF16_ONES_PAIR);
    int t = threadIdx.x;
    size_t blockStart = (size_t)blockIdx.x * MP_EPB;
    u32 rowBase = (u32)(blockStart / LBL_);
    for (int i = t; i < 48; i += 256) smax[i] = 0;
    __syncthreads();
    if (bf) {
        const u16* cm = (const u16*)CM;
        uint4 ch[8];
        size_t i0[8];
        #pragma unroll
        for (int u = 0; u < 8; ++u) {
            size_t idx0 = blockStart + ((size_t)u * 256 + t) * 8;
            i0[u] = idx0;
            ch[u] = (idx0 + 8 <= NCM) ? *(const uint4*)(cm + idx0)
                                      : make_uint4(0, 0, 0, 0);
        }
        #pragma unroll
        for (int u = 0; u < 8; ++u) {
            size_t idx0 = i0[u];
            if (idx0 + 8 <= NCM) {
                uint4 c4 = ch[u];
                if ((c4.x | c4.y | c4.z | c4.w) == 0) continue;
                u32 hw[4] = {c4.x, c4.y, c4.z, c4.w};
                #pragma unroll
                for (int d = 0; d < 4; ++d) {
                    u32 lo = hw[d] & 0xffff, hi = hw[d] >> 16;
                    if (lo) mp_hit((u32)idx0 + d*2,     bf2f(lo), pt, smax, rowBase);
                    if (hi) mp_hit((u32)idx0 + d*2 + 1, bf2f(hi), pt, smax, rowBase);
                }
            } else if (idx0 < NCM) {
                for (u32 e = 0; e < (u32)(NCM - idx0); ++e) {
                    u16 h = cm[idx0 + e];
                    if (h) mp_hit((u32)idx0 + e, bf2f(h), pt, smax, rowBase);
                }
            }
        }
    } else {
        const float* cm = (const float*)CM;
        #pragma unroll
        for (int u = 0; u < 16; ++u) {
            size_t idx0 = blockStart + ((size_t)u * 256 + t) * 4;
            if (idx0 >= NCM) continue;
            float v[4];
            if (idx0 + 4 <= NCM) {
                float4 f = *(const float4*)(cm + idx0);
                v[0] = f.x; v[1] = f.y; v[2] = f.z; v[3] = f.w;
            } else {
                v[0] = v[1] = v[2] = v[3] = 0.f;
                for (u32 e = 0; e < (u32)(NCM - idx0); ++e) v[e] = cm[idx0 + e];
            }
            if (v[0] == 0.f && v[1] == 0.f && v[2] == 0.f && v[3] == 0.f) continue;
            #pragma unroll
            for (int e = 0; e < 4; ++e)
                if (v[e] != 0.f) mp_hit((u32)idx0 + e, v[e], pt, smax, rowBase);
        }
    }
    __syncthreads();
    size_t lastIdx = blockStart + MP_EPB - 1;
    if (lastIdx >= NCM) lastIdx = NCM - 1;
    int nrows = (int)((u32)(lastIdx / LBL_) - rowBase) + 1;
    for (int s = t; s < nrows * 8; s += 256) {
        int v = smax[s];
        if (v != 0) {
            int rr = s >> 3, b = s & 7;
            atomicMax((int*)(out + (size_t)b * LBL_ + rowBase + rr), v);
        }
    }
}

extern "C" void kernel_launch(void* const* d_in, const int* in_sizes, int n_in,
                              void* d_out, int out_size, void* d_ws, size_t ws_size,
                              hipStream_t stream) {
    const void* hv   = d_in[0];
    const int* mask  = (const int*)d_in[1];
    const void* ln0g = d_in[2];
    const void* ln0b = d_in[3];
    const void* w_in = d_in[4];
    const void* b_in = d_in[5];
    const void* ln1g = d_in[6];
    const void* ln1b = d_in[7];
    const void* w_h  = d_in[8];
    const void* b_h  = d_in[9];
    const void* ln2g = d_in[10];
    const void* ln2b = d_in[11];
    const void* aw1  = d_in[12];
    const void* ab1  = d_in[13];
    const void* alng = d_in[14];
    const void* alnb = d_in[15];
    const void* aw2  = d_in[16];
    const void* ab2  = d_in[17];
    const void* ow1  = d_in[18];
    const void* ob1  = d_in[19];
    const void* olng = d_in[20];
    const void* olnb = d_in[21];
    const void* ow2  = d_in[22];
    const void* ob2  = d_in[23];
    const void* CM   = d_in[24];
    const u32* probe = (const u32*)ln0g;
    float* out = (float*)d_out;

    float* f = (float*)d_ws;
    float2* st1 = (float2*)f;                    // [4][8192] float2 = 65536 floats
    float2* st2 = st1 + 32768;                   // [4][8192] float2 = 65536 floats
    float* lg    = f + 131072;                   // 65536  [8,8,1024]
    float* hp    = lg + 65536;                   // 16384
    float* ha    = hp + 16384;                   // 16384  (LN'd h)
    float* part1 = ha + 16384;                   // 32*8*2048 = 524288
    float* part2 = part1 + 524288;               // 32*8*4766 = 1220096
    float* pt    = part2 + 1220096;              // 38128  (transposed sigmoid)
    u16* x0  = (u16*)(pt + 38128);               // 8192*1024
    u16* x1  = x0 + 8388608;                     // 8192*256
    u16* x2  = x1 + 2097152;                     // 8192*256
    u16* wt1 = x2 + 2097152;                     // 256*1024
    u16* wt2 = wt1 + 262144;                     // 256*256
    u16* wt3 = wt2 + 65536;                      // 64*256

    // 1: LN0 (wave-per-row) + transposes
    prep_k<<<M_/4 + 84, 256, 0, stream>>>(hv, ln0g, ln0b, x0,
                                          w_in, wt1, w_h, wt2, aw1, wt3, probe);
    // 2-3: trunk GEMMs, 64x64 tiles grid (128,4), BK=64 dbuf, plain-stat stores
    gemm_mfma<<<dim3(M_/64, 4), 256, 0, stream>>>(x0, 2, nullptr, nullptr, nullptr,
                                                  wt1, b_in, x1, (float*)st1,
                                                  M_, H_, F_, probe);
    gemm_mfma<<<dim3(M_/64, 4), 256, 0, stream>>>(x1, 1, st1, ln1g, ln1b,
                                                  wt2, b_h, x2, (float*)st2,
                                                  M_, H_, H_, probe);
    // 4: gemm3 + fused LN(64) + attn logits
    gemm3_attn_k<<<M_/64, 256, 0, stream>>>(x2, st2, ln2g, ln2b, wt3, ab1,
                                            alng, alnb, aw2, ab2, mask, lg, probe);
    // 5: fused softmax + pooling + LN2-affine
    attnpool_k<<<B_*NH_, 1024, 0, stream>>>(lg, st2, x2, ln2g, ln2b, hp, probe);
    // 6-9: output block — gemv partials (KC=64, 32 chunks) + 32-deep ILP combines
    gemv_ilp_part_k<64><<<dim3(OD_/512, NCH), 256, 0, stream>>>(hp, ow1, part1,
                                                                OD_, OD_, probe);
    out_ln_k<<<B_, 1024, 0, stream>>>(part1, ha, ob1, olng, olnb, probe);
    gemv_ilp_part_k<64><<<dim3((LBL_+511)/512, NCH), 256, 0, stream>>>(ha, ow2, part2,
                                                                       OD_, LBL_, probe);
    sigmoid_t_k<<<dim3((LBL_+255)/256, 8), 256, 0, stream>>>(part2, ob2, pt, out, probe);
    // 10: GO max-product
    maxprod3_k<<<MP_NB, 256, 0, stream>>>(pt, CM, out, probe);
}